// Round 1
// baseline (79.086 us; speedup 1.0000x reference)
//
#include <hip/hip_runtime.h>
#include <stdint.h>

// Problem constants
#define B_SZ 256
#define C_IN 3072
#define C_OUT 1024
#define WORDS 16          // 1024 groups / 64 bits per uint64
// Plane layout per word: [P0,P1,P2,Z0,Z1,Z2]
//   Pk bit g = (elem[3g+k] > 0), Zk bit g = (elem[3g+k] != 0)

// ---------------- pack x: [B][96] uint64 (b-major, word*6+plane) -------------
__global__ __launch_bounds__(256) void pack_x(const float* __restrict__ x,
                                              uint64_t* __restrict__ xpk) {
    int wid  = blockIdx.x * 4 + (threadIdx.x >> 6);   // 0..4095 (B*WORDS)
    int lane = threadIdx.x & 63;
    int b    = wid >> 4;
    int word = wid & 15;
    const float* row = x + (size_t)b * C_IN + word * 192;
    uint64_t* dst = xpk + (size_t)b * 96 + word * 6;
    float v0 = row[3 * lane + 0];
    float v1 = row[3 * lane + 1];
    float v2 = row[3 * lane + 2];
    uint64_t p0 = __ballot(v0 > 0.0f), z0 = __ballot(v0 != 0.0f);
    uint64_t p1 = __ballot(v1 > 0.0f), z1 = __ballot(v1 != 0.0f);
    uint64_t p2 = __ballot(v2 > 0.0f), z2 = __ballot(v2 != 0.0f);
    if (lane == 0) {
        dst[0] = p0; dst[1] = p1; dst[2] = p2;
        dst[3] = z0; dst[4] = z1; dst[5] = z2;
    }
}

// ------------- pack w: [word][plane][C_OUT] uint64 (c-minor, coalesced) ------
__global__ __launch_bounds__(256) void pack_w(const float* __restrict__ w,
                                              uint64_t* __restrict__ wpk) {
    int wid  = blockIdx.x * 4 + (threadIdx.x >> 6);   // 0..16383 (C_OUT*WORDS)
    int lane = threadIdx.x & 63;
    int c    = wid >> 4;
    int word = wid & 15;
    const float* row = w + (size_t)c * C_IN + word * 192;
    float v0 = row[3 * lane + 0];
    float v1 = row[3 * lane + 1];
    float v2 = row[3 * lane + 2];
    uint64_t p0 = __ballot(v0 > 0.0f), z0 = __ballot(v0 != 0.0f);
    uint64_t p1 = __ballot(v1 > 0.0f), z1 = __ballot(v1 != 0.0f);
    uint64_t p2 = __ballot(v2 > 0.0f), z2 = __ballot(v2 != 0.0f);
    if (lane == 0) {
        uint64_t* base = wpk + (size_t)word * 6 * C_OUT + c;
        base[0 * C_OUT] = p0; base[1 * C_OUT] = p1; base[2 * C_OUT] = p2;
        base[3 * C_OUT] = z0; base[4 * C_OUT] = z1; base[5 * C_OUT] = z2;
    }
}

// ---------------- main: per (b,c) ternary majority reduction ----------------
#define BT 2   // b-rows per block / per thread
__global__ __launch_bounds__(256) void maj_main(const uint64_t* __restrict__ wpk,
                                                const uint64_t* __restrict__ xpk,
                                                float* __restrict__ out) {
    __shared__ uint64_t xs[BT * 96];
    int tid = threadIdx.x;
    int bt  = blockIdx.x >> 2;        // 0..127
    int ct  = blockIdx.x & 3;         // 0..3
    int b0  = bt * BT;
    int c   = ct * 256 + tid;

    for (int i = tid; i < BT * 96; i += 256)
        xs[i] = xpk[(size_t)b0 * 96 + i];
    __syncthreads();

    int accP[BT], accN[BT];
#pragma unroll
    for (int i = 0; i < BT; ++i) { accP[i] = 0; accN[i] = 0; }

    for (int word = 0; word < WORDS; ++word) {
        const uint64_t* wb = wpk + (size_t)word * 6 * C_OUT + c;
        uint64_t WP0 = wb[0 * C_OUT], WP1 = wb[1 * C_OUT], WP2 = wb[2 * C_OUT];
        uint64_t WZ0 = wb[3 * C_OUT], WZ1 = wb[4 * C_OUT], WZ2 = wb[5 * C_OUT];
#pragma unroll
        for (int bi = 0; bi < BT; ++bi) {
            const uint64_t* xr = &xs[bi * 96 + word * 6];
            // product signs per k-position (ternary-exact)
            uint64_t t0 = xr[0] ^ WP0, z0 = xr[3] & WZ0;
            uint64_t t1 = xr[1] ^ WP1, z1 = xr[4] & WZ1;
            uint64_t t2 = xr[2] ^ WP2, z2 = xr[5] & WZ2;
            uint64_t P0 = z0 & ~t0, N0 = z0 & t0;
            uint64_t P1 = z1 & ~t1, N1 = z1 & t1;
            uint64_t P2 = z2 & ~t2, N2 = z2 & t2;
            // 2-bit counts of +1 products (A) and -1 products (Bc) per group
            uint64_t a0 = P0 ^ P1 ^ P2;
            uint64_t a1 = (P0 & P1) | (P2 & (P0 | P1));
            uint64_t c0 = N0 ^ N1 ^ N2;
            uint64_t c1 = (N0 & N1) | (N2 & (N0 | N1));
            // clip(sum) = sign(A - Bc): compare 2-bit numbers
            uint64_t ne1 = a1 ^ c1;
            uint64_t gt = (a1 & ~c1) | (~ne1 & (a0 & ~c0));
            uint64_t lt = (c1 & ~a1) | (~ne1 & (c0 & ~a0));
            accP[bi] += __popcll(gt);
            accN[bi] += __popcll(lt);
        }
    }
#pragma unroll
    for (int bi = 0; bi < BT; ++bi)
        out[(size_t)(b0 + bi) * C_OUT + c] = 2.25f * (float)(accP[bi] - accN[bi]);
}

extern "C" void kernel_launch(void* const* d_in, const int* in_sizes, int n_in,
                              void* d_out, int out_size, void* d_ws, size_t ws_size,
                              hipStream_t stream) {
    const float* x = (const float*)d_in[0];   // [256, 3072] f32
    const float* w = (const float*)d_in[1];   // [1024, 3072] f32
    float* out = (float*)d_out;               // [256, 1024] f32

    // workspace layout: wpk (786432 B) | xpk (196608 B)  -> 983040 B total
    uint64_t* wpk = (uint64_t*)d_ws;
    uint64_t* xpk = (uint64_t*)((char*)d_ws + (size_t)WORDS * 6 * C_OUT * 8);

    pack_x<<<(B_SZ * WORDS) / 4, 256, 0, stream>>>(x, xpk);
    pack_w<<<(C_OUT * WORDS) / 4, 256, 0, stream>>>(w, wpk);
    maj_main<<<(B_SZ / BT) * 4, 256, 0, stream>>>(wpk, xpk, out);
}

// Round 2
// 74.597 us; speedup vs baseline: 1.0602x; 1.0602x over previous
//
#include <hip/hip_runtime.h>
#include <stdint.h>

// Problem constants
#define B_SZ 256
#define C_IN 3072
#define C_OUT 1024
#define WORDS 16          // 1024 groups / 64 bits per uint64
#define XW (B_SZ * WORDS)   // 4096 x-pack wave-jobs
#define WW (C_OUT * WORDS)  // 16384 w-pack wave-jobs

// Bitplanes per (row, word): [P0,P1,P2,Z0,Z1,Z2]
//   Pk bit g = (elem[3g+k] > 0), Zk bit g = (elem[3g+k] != 0)
// xpk layout: [b][word*6 + plane]            (b-major; read via SMEM scalar loads)
// wpk layout: [word][c][plane] (6 contiguous uint64 per (word,c) -> dwordx4 loads)

__global__ __launch_bounds__(256) void pack_both(const float* __restrict__ x,
                                                 const float* __restrict__ w,
                                                 uint64_t* __restrict__ xpk,
                                                 uint64_t* __restrict__ wpk) {
    int wid  = blockIdx.x * 4 + (threadIdx.x >> 6);   // one wave per (row,word) job
    int lane = threadIdx.x & 63;
    const float* row;
    uint64_t* dst;
    if (wid < XW) {
        int b = wid >> 4, word = wid & 15;
        row = x + (size_t)b * C_IN + word * 192;
        dst = xpk + (size_t)b * 96 + word * 6;
    } else {
        int id = wid - XW;
        int c = id >> 4, word = id & 15;
        row = w + (size_t)c * C_IN + word * 192;
        dst = wpk + ((size_t)word * C_OUT + c) * 6;
    }
    float v0 = row[3 * lane + 0];
    float v1 = row[3 * lane + 1];
    float v2 = row[3 * lane + 2];
    uint64_t p0 = __ballot(v0 > 0.0f), z0 = __ballot(v0 != 0.0f);
    uint64_t p1 = __ballot(v1 > 0.0f), z1 = __ballot(v1 != 0.0f);
    uint64_t p2 = __ballot(v2 > 0.0f), z2 = __ballot(v2 != 0.0f);
    if (lane == 0) {
        dst[0] = p0; dst[1] = p1; dst[2] = p2;
        dst[3] = z0; dst[4] = z1; dst[5] = z2;
    }
}

// ---------------- main: per (b,c) ternary majority reduction ----------------
#define BT 2   // b-rows per thread
__global__ __launch_bounds__(256) void maj_main(const uint64_t* __restrict__ wpk,
                                                const uint64_t* __restrict__ xpk,
                                                float* __restrict__ out) {
    int tid = threadIdx.x;
    int bt  = blockIdx.x >> 2;        // 0..127
    int ct  = blockIdx.x & 3;         // 0..3
    int b0  = bt * BT;
    int c   = ct * 256 + tid;

    int accP[BT], accN[BT];
#pragma unroll
    for (int i = 0; i < BT; ++i) { accP[i] = 0; accN[i] = 0; }

#pragma unroll 2
    for (int word = 0; word < WORDS; ++word) {
        const uint64_t* wb = wpk + ((size_t)word * C_OUT + c) * 6;  // 48 B contiguous
        uint64_t WP0 = wb[0], WP1 = wb[1], WP2 = wb[2];
        uint64_t WZ0 = wb[3], WZ1 = wb[4], WZ2 = wb[5];
#pragma unroll
        for (int bi = 0; bi < BT; ++bi) {
            // wave-uniform address -> scalar (SMEM) loads, parallel to VALU pipe
            const uint64_t* xr = xpk + (size_t)(b0 + bi) * 96 + word * 6;
            uint64_t t0 = xr[0] ^ WP0, t1 = xr[1] ^ WP1, t2 = xr[2] ^ WP2;
            uint64_t z0 = xr[3] & WZ0, z1 = xr[4] & WZ1, z2 = xr[5] & WZ2;
            // ternary product: P = (+1), N = (-1) indicator per k-slot
            uint64_t N0 = z0 & t0, N1 = z1 & t1, N2 = z2 & t2;
            uint64_t P0 = z0 ^ N0, P1 = z1 ^ N1, P2 = z2 ^ N2;   // z & ~t
            // 2-bit carry-save counts of +1s (a) and -1s (cc) per group
            uint64_t a0 = P0 ^ P1 ^ P2;
            uint64_t a1 = (P0 & P1) | (P2 & (P0 | P1));
            uint64_t c0 = N0 ^ N1 ^ N2;
            uint64_t c1 = (N0 & N1) | (N2 & (N0 | N1));
            // clip(sum) = sign(a - cc): 2-bit comparator
            uint64_t ne1 = a1 ^ c1;
            uint64_t gt = (a1 & ~c1) | (~ne1 & (a0 & ~c0));
            uint64_t lt = (c1 & ~a1) | (~ne1 & (c0 & ~a0));
            accP[bi] += __popcll(gt);
            accN[bi] += __popcll(lt);
        }
    }
#pragma unroll
    for (int bi = 0; bi < BT; ++bi)
        out[(size_t)(b0 + bi) * C_OUT + c] = 2.25f * (float)(accP[bi] - accN[bi]);
}

extern "C" void kernel_launch(void* const* d_in, const int* in_sizes, int n_in,
                              void* d_out, int out_size, void* d_ws, size_t ws_size,
                              hipStream_t stream) {
    const float* x = (const float*)d_in[0];   // [256, 3072] f32
    const float* w = (const float*)d_in[1];   // [1024, 3072] f32
    float* out = (float*)d_out;               // [256, 1024] f32

    // workspace layout: wpk (786432 B) | xpk (196608 B)
    uint64_t* wpk = (uint64_t*)d_ws;
    uint64_t* xpk = (uint64_t*)((char*)d_ws + (size_t)WORDS * 6 * C_OUT * 8);

    pack_both<<<(XW + WW) / 4, 256, 0, stream>>>(x, w, xpk, wpk);
    maj_main<<<(B_SZ / BT) * 4, 256, 0, stream>>>(wpk, xpk, out);
}